// Round 1
// baseline (1996.096 us; speedup 1.0000x reference)
//
#include <hip/hip_runtime.h>
#include <math.h>

#define N_NODES 524288
#define E 64
#define NC 8
#define NH 4
#define BPS 2048  // blocks per side in kernel A (2048*256 == N_NODES)

// ---- workspace layout (float offsets) ----
#define OFF_QK_V    0      // qk[c][h][j]  c*256+h*64+j  (2048)
#define OFF_QB_V    2048   // qb[c][h]     c*4+h         (32)
#define OFF_QK_C    2080
#define OFF_QB_C    4128
#define OFF_ACC_V   4160   // 2600 floats
#define OFF_ACC_C   6760
#define OFF_FUSED_V 9360   // 512
#define OFF_FUSED_C 9872
// acc internal layout:
#define ACC_SXW 0      // [(h*64+j)*8 + c]  (2048)  sum of p_h * xs_j per class
#define ACC_AXS 2048   // [j*8 + c]         (512)   sum of xs_j per class
#define ACC_P   2560   // [h*8 + c]         (32)    sum of p_h per class
#define ACC_CNT 2592   // [c]               (8)
#define ACC_TOTAL 2600

// ---------------- kernel Q: q -> folded (qk, qb); also zero accumulators ----------------
__global__ __launch_bounds__(512) void kQ(
    const float* __restrict__ sem_v, const float* __restrict__ sem_c,
    const float* __restrict__ Wqkv_v, const float* __restrict__ bqkv_v,
    const float* __restrict__ Wqkv_c, const float* __restrict__ bqkv_c,
    float* __restrict__ ws)
{
    const int side = blockIdx.x;
    const float* sem  = side ? sem_c  : sem_v;
    const float* Wqkv = side ? Wqkv_c : Wqkv_v;
    const float* bqkv = side ? bqkv_c : bqkv_v;
    float* qk   = ws + (side ? OFF_QK_C  : OFF_QK_V);
    float* qb   = ws + (side ? OFF_QB_C  : OFF_QB_V);
    float* gacc = ws + (side ? OFF_ACC_C : OFF_ACC_V);
    const int tid = threadIdx.x;

    // zero global accumulators for this side (runs before kA in stream order)
    for (int i = tid; i < ACC_TOTAL; i += 512) gacc[i] = 0.0f;

    __shared__ float s_q[NC][E];
    {   // q[c][e] = (bq[e] + sem[c]·Wq[e]) * (1/sqrt(16))
        const int c = tid >> 6, e = tid & 63;
        const float* Wq = Wqkv;          // rows 0..63
        const float* bq = bqkv;
        float a = bq[e];
        for (int j = 0; j < E; ++j) a += sem[c*E + j] * Wq[e*E + j];
        s_q[c][e] = a * 0.25f;
    }
    __syncthreads();

    const float* Wk = Wqkv + E*E;        // rows 64..127
    const float* bk = bqkv + E;
    // qk[c][h][j] = sum_d Wk[h*16+d][j] * q[c][h*16+d]
    for (int r = 0; r < 4; ++r) {
        int idx = r*512 + tid;           // idx = c*256 + h*64 + j
        int c = idx >> 8, h = (idx >> 6) & 3, j = idx & 63;
        float a = 0.0f;
        for (int d = 0; d < 16; ++d) a += Wk[(h*16+d)*E + j] * s_q[c][h*16+d];
        qk[idx] = a;
    }
    // qb[c][h] = sum_d bk[h*16+d] * q[c][h*16+d]
    if (tid < 32) {
        int c = tid >> 2, h = tid & 3;
        float a = 0.0f;
        for (int d = 0; d < 16; ++d) a += bk[h*16+d] * s_q[c][h*16+d];
        qb[tid] = a;
    }
}

// ---------------- kernel A: per-node xs, scores, p, segment accumulation ----------------
__global__ __launch_bounds__(256) void kA(
    const float* __restrict__ xv, const float* __restrict__ xc,
    const int* __restrict__ clsv, const int* __restrict__ clsc,
    const float* __restrict__ Ws_v, const float* __restrict__ bs_v,
    const float* __restrict__ Ws_c, const float* __restrict__ bs_c,
    float* __restrict__ ws)
{
    const int bid  = blockIdx.x;
    const int side = bid >= BPS;
    const float* x   = side ? xc    : xv;
    const int*   cls = side ? clsc  : clsv;
    const float* Ws  = side ? Ws_c  : Ws_v;
    const float* bs  = side ? bs_c  : bs_v;
    const float* qk_g = ws + (side ? OFF_QK_C : OFF_QK_V);
    const float* qb_g = ws + (side ? OFF_QB_C : OFF_QB_V);
    float* gacc = ws + (side ? OFF_ACC_C : OFF_ACC_V);
    const int tid = threadIdx.x;

    __shared__ float s_qk[NC * 260];     // c-stride 260 (pad) -> conflict-free b128 reads
    __shared__ float s_qb[32];
    __shared__ float s_acc[ACC_TOTAL];

    for (int i = tid; i < 2048; i += 256) {
        int c = i >> 8, r = i & 255;
        s_qk[c*260 + r] = qk_g[i];
    }
    if (tid < 32) s_qb[tid] = qb_g[tid];
    for (int i = tid; i < ACC_TOTAL; i += 256) s_acc[i] = 0.0f;
    __syncthreads();

    const int node = (bid & (BPS - 1)) * 256 + tid;
    const int myc  = cls[node];
    const float* xr = x + node * 64;

    float xl[64];
    #pragma unroll
    for (int j4 = 0; j4 < 16; ++j4) {
        float4 t = reinterpret_cast<const float4*>(xr)[j4];
        xl[j4*4+0] = t.x; xl[j4*4+1] = t.y; xl[j4*4+2] = t.z; xl[j4*4+3] = t.w;
    }

    // xs = x @ Ws^T + bs   (4-way ILP, weights are wave-uniform -> scalar loads)
    float xs[64];
    #pragma unroll
    for (int e4 = 0; e4 < 16; ++e4) {
        float a0 = bs[e4*4+0], a1 = bs[e4*4+1], a2 = bs[e4*4+2], a3 = bs[e4*4+3];
        #pragma unroll
        for (int j = 0; j < 64; ++j) {
            const float xj = xl[j];
            a0 += xj * Ws[(e4*4+0)*64 + j];
            a1 += xj * Ws[(e4*4+1)*64 + j];
            a2 += xj * Ws[(e4*4+2)*64 + j];
            a3 += xj * Ws[(e4*4+3)*64 + j];
        }
        xs[e4*4+0] = a0; xs[e4*4+1] = a1; xs[e4*4+2] = a2; xs[e4*4+3] = a3;
    }

    // scores[h] = xs · qk[myc][h] + qb[myc][h]   (Wk folded into qk)
    float sc0 = s_qb[myc*4+0], sc1 = s_qb[myc*4+1], sc2 = s_qb[myc*4+2], sc3 = s_qb[myc*4+3];
    const float* qkb = s_qk + myc*260;
    #pragma unroll
    for (int j4 = 0; j4 < 16; ++j4) {
        const float b0 = xl[0]; // keep optimizer from resurrecting xl (no-op)
        (void)b0;
        float4 q0 = *reinterpret_cast<const float4*>(qkb + 0*64 + j4*4);
        float4 q1 = *reinterpret_cast<const float4*>(qkb + 1*64 + j4*4);
        float4 q2 = *reinterpret_cast<const float4*>(qkb + 2*64 + j4*4);
        float4 q3 = *reinterpret_cast<const float4*>(qkb + 3*64 + j4*4);
        const float x0 = xs[j4*4+0], x1 = xs[j4*4+1], x2 = xs[j4*4+2], x3 = xs[j4*4+3];
        sc0 += x0*q0.x + x1*q0.y + x2*q0.z + x3*q0.w;
        sc1 += x0*q1.x + x1*q1.y + x2*q1.z + x3*q1.w;
        sc2 += x0*q2.x + x1*q2.y + x2*q2.z + x3*q2.w;
        sc3 += x0*q3.x + x1*q3.y + x2*q3.z + x3*q3.w;
    }
    // softmax-max skipped: |scores| << 1 with this weight scale; w = p/Z is shift-invariant
    const float p0 = __expf(sc0), p1 = __expf(sc1), p2 = __expf(sc2), p3 = __expf(sc3);

    // segment accumulation into LDS (Wv GEMM deferred by linearity: accumulate p_h * xs)
    #pragma unroll
    for (int j = 0; j < 64; ++j) {
        const float v = xs[j];
        atomicAdd(&s_acc[ACC_AXS + j*8 + myc], v);
        atomicAdd(&s_acc[ACC_SXW + (0*64 + j)*8 + myc], p0 * v);
        atomicAdd(&s_acc[ACC_SXW + (1*64 + j)*8 + myc], p1 * v);
        atomicAdd(&s_acc[ACC_SXW + (2*64 + j)*8 + myc], p2 * v);
        atomicAdd(&s_acc[ACC_SXW + (3*64 + j)*8 + myc], p3 * v);
    }
    atomicAdd(&s_acc[ACC_P + 0*8 + myc], p0);
    atomicAdd(&s_acc[ACC_P + 1*8 + myc], p1);
    atomicAdd(&s_acc[ACC_P + 2*8 + myc], p2);
    atomicAdd(&s_acc[ACC_P + 3*8 + myc], p3);
    atomicAdd(&s_acc[ACC_CNT + myc], 1.0f);

    __syncthreads();
    for (int i = tid; i < ACC_TOTAL; i += 256) atomicAdd(&gacc[i], s_acc[i]);
}

// ---------------- kernel C: class-level finalize -> fused[c][e] ----------------
__global__ __launch_bounds__(512) void kC(
    const float* __restrict__ sem_v, const float* __restrict__ sem_c,
    const float* __restrict__ Wqkv_v, const float* __restrict__ bqkv_v,
    const float* __restrict__ Wqkv_c, const float* __restrict__ bqkv_c,
    const float* __restrict__ Wo_v, const float* __restrict__ bo_v,
    const float* __restrict__ Wo_c, const float* __restrict__ bo_c,
    const float* __restrict__ Wr_v, const float* __restrict__ br_v,
    const float* __restrict__ Wr_c, const float* __restrict__ br_c,
    const float* __restrict__ Wg_v, const float* __restrict__ bg_v,
    const float* __restrict__ Wg_c, const float* __restrict__ bg_c,
    const float* __restrict__ gamma, const float* __restrict__ beta,
    float* __restrict__ ws)
{
    const int side = blockIdx.x;
    const float* sem  = side ? sem_c  : sem_v;
    const float* Wqkv = side ? Wqkv_c : Wqkv_v;
    const float* bqkv = side ? bqkv_c : bqkv_v;
    const float* Wo = side ? Wo_c : Wo_v;  const float* bo = side ? bo_c : bo_v;
    const float* Wr = side ? Wr_c : Wr_v;  const float* br = side ? br_c : br_v;
    const float* Wg = side ? Wg_c : Wg_v;  const float* bg = side ? bg_c : bg_v;
    const float* gacc = ws + (side ? OFF_ACC_C : OFF_ACC_V);
    float* fused = ws + (side ? OFF_FUSED_C : OFF_FUSED_V);
    const float* Wv = Wqkv + 2*E*E;
    const float* bv = bqkv + 2*E;

    const int tid = threadIdx.x;
    const int c = tid >> 6, e = tid & 63, h = e >> 4;   // one wave per class

    __shared__ float s_a[NC][E];   // attn input (pre out-proj)
    __shared__ float s_b[NC][E];   // attn (post out-proj)
    __shared__ float s_old[NC][E];
    __shared__ float s_new[NC][E];

    // pre_o = bv + ( (sum p*xs)/Z ) @ Wv^T
    const float Z = gacc[ACC_P + h*8 + c];
    float s = 0.0f;
    for (int j = 0; j < 64; ++j) s += gacc[ACC_SXW + (h*64 + j)*8 + c] * Wv[e*64 + j];
    s_a[c][e] = bv[e] + s / Z;
    __syncthreads();

    float s2 = bo[e];
    for (int j = 0; j < 64; ++j) s2 += s_a[c][j] * Wo[e*64 + j];
    s_b[c][e] = s2;
    const float cnt = gacc[ACC_CNT + c];
    const float oldv = gacc[ACC_AXS + e*8 + c] / fmaxf(cnt, 1.0f);
    s_old[c][e] = oldv;
    __syncthreads();

    float s3 = br[e];
    for (int j = 0; j < 64; ++j) s3 += sem[c*64 + j] * Wr[e*128 + j];
    for (int j = 0; j < 64; ++j) s3 += s_b[c][j]    * Wr[e*128 + 64 + j];
    s_new[c][e] = s3;
    __syncthreads();

    float s4 = bg[e];
    for (int j = 0; j < 64; ++j) s4 += s_old[c][j] * Wg[e*128 + j];
    for (int j = 0; j < 64; ++j) s4 += s_new[c][j] * Wg[e*128 + 64 + j];
    const float g = 1.0f / (1.0f + __expf(-s4));
    const float f = g * oldv + (1.0f - g) * s3;

    // LayerNorm across the 64 lanes of this wave (= one class row)
    float sum = f;
    for (int m = 32; m >= 1; m >>= 1) sum += __shfl_xor(sum, m, 64);
    const float mu = sum * (1.0f/64.0f);
    const float d  = f - mu;
    float sq = d * d;
    for (int m = 32; m >= 1; m >>= 1) sq += __shfl_xor(sq, m, 64);
    const float var = sq * (1.0f/64.0f);
    fused[c*64 + e] = d * rsqrtf(var + 1e-5f) * gamma[e] + beta[e];
}

// ---------------- kernel D: out[n] = fused[cls[n]] * x[n] ----------------
__global__ __launch_bounds__(256) void kD(
    const float* __restrict__ xv, const float* __restrict__ xc,
    const int* __restrict__ clsv, const int* __restrict__ clsc,
    const float* __restrict__ ws, float* __restrict__ out)
{
    const int stride = gridDim.x * blockDim.x;
    const int TOT = 2 * N_NODES * 16;   // float4 count
    for (int i = blockIdx.x * blockDim.x + threadIdx.x; i < TOT; i += stride) {
        const int side  = i >= N_NODES * 16;
        const int local = side ? i - N_NODES * 16 : i;
        const int n = local >> 4;
        const int cc = side ? clsc[n] : clsv[n];
        const float* fu = ws + (side ? OFF_FUSED_C : OFF_FUSED_V);
        const float4 f  = reinterpret_cast<const float4*>(fu)[cc*16 + (local & 15)];
        const float* x  = side ? xc : xv;
        const float4 x4 = reinterpret_cast<const float4*>(x)[local];
        float4 o;
        o.x = f.x * x4.x; o.y = f.y * x4.y; o.z = f.z * x4.z; o.w = f.w * x4.w;
        reinterpret_cast<float4*>(out)[i] = o;
    }
}

extern "C" void kernel_launch(void* const* d_in, const int* in_sizes, int n_in,
                              void* d_out, int out_size, void* d_ws, size_t ws_size,
                              hipStream_t stream) {
    const float* v      = (const float*)d_in[0];
    const float* c      = (const float*)d_in[1];
    const float* v_sem  = (const float*)d_in[2];
    const float* c_sem  = (const float*)d_in[3];
    const int*   v_cls  = (const int*)d_in[4];
    const int*   c_cls  = (const int*)d_in[5];
    const float* Ws_v   = (const float*)d_in[6],  *bs_v   = (const float*)d_in[7];
    const float* Ws_c   = (const float*)d_in[8],  *bs_c   = (const float*)d_in[9];
    const float* Wqkv_v = (const float*)d_in[10], *bqkv_v = (const float*)d_in[11];
    const float* Wo_v   = (const float*)d_in[12], *bo_v   = (const float*)d_in[13];
    const float* Wqkv_c = (const float*)d_in[14], *bqkv_c = (const float*)d_in[15];
    const float* Wo_c   = (const float*)d_in[16], *bo_c   = (const float*)d_in[17];
    const float* Wr_v   = (const float*)d_in[18], *br_v   = (const float*)d_in[19];
    const float* Wr_c   = (const float*)d_in[20], *br_c   = (const float*)d_in[21];
    const float* Wg_v   = (const float*)d_in[22], *bg_v   = (const float*)d_in[23];
    const float* Wg_c   = (const float*)d_in[24], *bg_c   = (const float*)d_in[25];
    const float* gamma  = (const float*)d_in[26], *beta   = (const float*)d_in[27];
    float* ws  = (float*)d_ws;
    float* out = (float*)d_out;

    kQ<<<2, 512, 0, stream>>>(v_sem, c_sem, Wqkv_v, bqkv_v, Wqkv_c, bqkv_c, ws);
    kA<<<2*BPS, 256, 0, stream>>>(v, c, v_cls, c_cls, Ws_v, bs_v, Ws_c, bs_c, ws);
    kC<<<2, 512, 0, stream>>>(v_sem, c_sem, Wqkv_v, bqkv_v, Wqkv_c, bqkv_c,
                              Wo_v, bo_v, Wo_c, bo_c, Wr_v, br_v, Wr_c, br_c,
                              Wg_v, bg_v, Wg_c, bg_c, gamma, beta, ws);
    kD<<<4096, 256, 0, stream>>>(v, c, v_cls, c_cls, ws, out);
}

// Round 2
// 1916.120 us; speedup vs baseline: 1.0417x; 1.0417x over previous
//
#include <hip/hip_runtime.h>
#include <math.h>

#define N_NODES 524288
#define E 64
#define NC 8
#define BPS2 256   // kA blocks per side
#define TILE 256   // nodes per tile
#define ITERS (N_NODES / (BPS2 * TILE))  // 8 tiles per block

// ---- workspace layout (float offsets) ----
#define OFF_QK_V    0      // qk[c][h][j]  c*256+h*64+j  (2048)
#define OFF_QB_V    2048   // qb[c][h]     c*4+h         (32)
#define OFF_QK_C    2080
#define OFF_QB_C    4128
#define OFF_ACC_V   4160   // 2600 floats
#define OFF_ACC_C   6760
#define OFF_FUSED_V 9360   // 512
#define OFF_FUSED_C 9872
// acc internal layout (gacc):
#define ACC_SXW 0      // [(h*64+j)*8 + c]  (2048)  sum of p_h * xs_j per class
#define ACC_AXS 2048   // [j*8 + c]         (512)   sum of xs_j per class
#define ACC_P   2560   // [h*8 + c]         (32)    sum of p_h per class
#define ACC_CNT 2592   // [c]               (8)
#define ACC_TOTAL 2600

typedef __attribute__((ext_vector_type(8))) short bf16x8;
typedef __attribute__((ext_vector_type(4))) float f32x4;

__device__ __forceinline__ unsigned short f2bf(float f) {
    union { float f; unsigned u; } v; v.f = f;
    return (unsigned short)((v.u + 0x7fffu + ((v.u >> 16) & 1u)) >> 16);  // RNE
}
__device__ __forceinline__ float bf2f(unsigned short s) {
    union { unsigned u; float f; } v; v.u = ((unsigned)s) << 16;
    return v.f;
}
__device__ __forceinline__ void unpack2(unsigned u, float& a, float& b) {
    union { unsigned u; float f; } lo, hi;
    lo.u = u << 16; hi.u = u & 0xffff0000u;
    a = lo.f; b = hi.f;
}
__device__ __forceinline__ bf16x8 load8bf(const float* p) {
    float4 a = *(const float4*)p;
    float4 b = *(const float4*)(p + 4);
    bf16x8 r;
    r[0] = (short)f2bf(a.x); r[1] = (short)f2bf(a.y);
    r[2] = (short)f2bf(a.z); r[3] = (short)f2bf(a.w);
    r[4] = (short)f2bf(b.x); r[5] = (short)f2bf(b.y);
    r[6] = (short)f2bf(b.z); r[7] = (short)f2bf(b.w);
    return r;
}

// ---------------- kernel Q: q -> folded (qk, qb); also zero accumulators ----------------
__global__ __launch_bounds__(512) void kQ(
    const float* __restrict__ sem_v, const float* __restrict__ sem_c,
    const float* __restrict__ Wqkv_v, const float* __restrict__ bqkv_v,
    const float* __restrict__ Wqkv_c, const float* __restrict__ bqkv_c,
    float* __restrict__ ws)
{
    const int side = blockIdx.x;
    const float* sem  = side ? sem_c  : sem_v;
    const float* Wqkv = side ? Wqkv_c : Wqkv_v;
    const float* bqkv = side ? bqkv_c : bqkv_v;
    float* qk   = ws + (side ? OFF_QK_C  : OFF_QK_V);
    float* qb   = ws + (side ? OFF_QB_C  : OFF_QB_V);
    float* gacc = ws + (side ? OFF_ACC_C : OFF_ACC_V);
    const int tid = threadIdx.x;

    for (int i = tid; i < ACC_TOTAL; i += 512) gacc[i] = 0.0f;

    __shared__ float s_q[NC][E];
    {   // q[c][e] = (bq[e] + sem[c]·Wq[e]) * (1/sqrt(16))
        const int c = tid >> 6, e = tid & 63;
        const float* Wq = Wqkv;
        const float* bq = bqkv;
        float a = bq[e];
        for (int j = 0; j < E; ++j) a += sem[c*E + j] * Wq[e*E + j];
        s_q[c][e] = a * 0.25f;
    }
    __syncthreads();

    const float* Wk = Wqkv + E*E;
    const float* bk = bqkv + E;
    for (int r = 0; r < 4; ++r) {
        int idx = r*512 + tid;           // idx = c*256 + h*64 + j
        int c = idx >> 8, h = (idx >> 6) & 3, j = idx & 63;
        float a = 0.0f;
        for (int d = 0; d < 16; ++d) a += Wk[(h*16+d)*E + j] * s_q[c][h*16+d];
        qk[idx] = a;
    }
    if (tid < 32) {
        int c = tid >> 2, h = tid & 3;
        float a = 0.0f;
        for (int d = 0; d < 16; ++d) a += bk[h*16+d] * s_q[c][h*16+d];
        qb[tid] = a;
    }
}

// ---------------- kernel A: MFMA xs-GEMM + scores + segment accumulation ----------------
__global__ __launch_bounds__(256, 2) void kA(
    const float* __restrict__ xv, const float* __restrict__ xc,
    const int* __restrict__ clsv, const int* __restrict__ clsc,
    const float* __restrict__ Ws_v, const float* __restrict__ bs_v,
    const float* __restrict__ Ws_c, const float* __restrict__ bs_c,
    float* __restrict__ ws)
{
    const int bid  = blockIdx.x;
    const int side = bid >> 8;             // bid >= BPS2
    const float* x   = side ? xc   : xv;
    const int*   cls = side ? clsc : clsv;
    const float* Ws  = side ? Ws_c : Ws_v;
    const float* bs  = side ? bs_c : bs_v;
    const float* qk_g = ws + (side ? OFF_QK_C : OFF_QK_V);
    const float* qb_g = ws + (side ? OFF_QB_C : OFF_QB_V);
    float* gacc = ws + (side ? OFF_ACC_C : OFF_ACC_V);
    const int tid  = threadIdx.x;
    const int w    = tid >> 6;             // wave id (0..3)
    const int lane = tid & 63;

    __shared__ unsigned short XS[TILE * 72];     // xs tile, bf16, stride 72
    __shared__ unsigned short QK[32 * 72];       // qk bf16, row = h*8+c, stride 72
    __shared__ float s_qb[32];
    __shared__ float s_p[TILE * 4];              // p0..p3 per node
    __shared__ int   s_cl[TILE];                 // c*64 per node
    __shared__ float s_acc[5 * 512];             // [ch][c][e], ch: 0..3 = p_h*xs, 4 = xs
    __shared__ float s_P[32];                    // sum p  [h*8+c]
    __shared__ float s_cnt[8];

    // ---- block init ----
    for (int i = tid; i < 5*512; i += 256) s_acc[i] = 0.0f;
    if (tid < 32) { s_P[tid] = 0.0f; s_qb[tid] = qb_g[tid]; }
    if (tid < 8) s_cnt[tid] = 0.0f;
    for (int i = tid; i < 2048; i += 256) {
        int c = i >> 8, h = (i >> 6) & 3, j = i & 63;
        QK[(h*8 + c)*72 + j] = f2bf(qk_g[i]);
    }
    // B fragments: Ws^T, layout B[k][e]: lane holds col e = eb*16+(lane&15),
    // k = kb*32 + (lane>>4)*8 + j  -> 8 consecutive floats of Ws row e.
    bf16x8 Bf[4][2];
    {
        const int e_in = lane & 15, kg = lane >> 4;
        #pragma unroll
        for (int eb = 0; eb < 4; ++eb)
            #pragma unroll
            for (int kb = 0; kb < 2; ++kb)
                Bf[eb][kb] = load8bf(Ws + (eb*16 + e_in)*64 + kb*32 + kg*8);
    }
    __syncthreads();

    const int bloc = bid & (BPS2 - 1);
    for (int t = 0; t < ITERS; ++t) {
        const int tilebase = (bloc * ITERS + t) * TILE;

        // ---- GEMM: xs[64n x 64e] per wave via MFMA ----
        f32x4 acc[4][4];
        #pragma unroll
        for (int mb = 0; mb < 4; ++mb) {
            const int node = tilebase + w*64 + mb*16 + (lane & 15);
            const float* xp = x + node*64 + (lane >> 4)*8;
            bf16x8 A0 = load8bf(xp);
            bf16x8 A1 = load8bf(xp + 32);
            #pragma unroll
            for (int eb = 0; eb < 4; ++eb) {
                f32x4 c0 = {0.f, 0.f, 0.f, 0.f};
                c0 = __builtin_amdgcn_mfma_f32_16x16x32_bf16(A0, Bf[eb][0], c0, 0, 0, 0);
                c0 = __builtin_amdgcn_mfma_f32_16x16x32_bf16(A1, Bf[eb][1], c0, 0, 0, 0);
                acc[mb][eb] = c0;
            }
        }
        // add bias bs (C layout: col = eb*16+(lane&15))
        #pragma unroll
        for (int eb = 0; eb < 4; ++eb) {
            const float b = bs[eb*16 + (lane & 15)];
            #pragma unroll
            for (int mb = 0; mb < 4; ++mb) {
                acc[mb][eb][0] += b; acc[mb][eb][1] += b;
                acc[mb][eb][2] += b; acc[mb][eb][3] += b;
            }
        }

        // ---- XS writeback (bf16) — wave-private rows ----
        #pragma unroll
        for (int mb = 0; mb < 4; ++mb)
            #pragma unroll
            for (int eb = 0; eb < 4; ++eb)
                #pragma unroll
                for (int r = 0; r < 4; ++r) {
                    const int row = w*64 + mb*16 + (lane >> 4)*4 + r;
                    const int e   = eb*16 + (lane & 15);
                    XS[row*72 + e] = f2bf(acc[mb][eb][r]);
                }

        // ---- scores: thread <-> node, all 4 heads ----
        {
            const int n = tid;
            const int node = tilebase + n;
            const int c = cls[node];
            s_cl[n] = c * 64;
            const int rot0 = (n + (n >> 3)) & 7;
            float sc0 = s_qb[c*4+0], sc1 = s_qb[c*4+1], sc2 = s_qb[c*4+2], sc3 = s_qb[c*4+3];
            #pragma unroll
            for (int i = 0; i < 8; ++i) {
                const int ec = ((i + rot0) & 7) * 8;
                const uint4 xv4 = *(const uint4*)&XS[n*72 + ec];
                float xf[8];
                unpack2(xv4.x, xf[0], xf[1]); unpack2(xv4.y, xf[2], xf[3]);
                unpack2(xv4.z, xf[4], xf[5]); unpack2(xv4.w, xf[6], xf[7]);
                #pragma unroll
                for (int h = 0; h < 4; ++h) {
                    const uint4 qv = *(const uint4*)&QK[(h*8 + c)*72 + ec];
                    float qf[8];
                    unpack2(qv.x, qf[0], qf[1]); unpack2(qv.y, qf[2], qf[3]);
                    unpack2(qv.z, qf[4], qf[5]); unpack2(qv.w, qf[6], qf[7]);
                    float d = xf[0]*qf[0] + xf[1]*qf[1] + xf[2]*qf[2] + xf[3]*qf[3]
                            + xf[4]*qf[4] + xf[5]*qf[5] + xf[6]*qf[6] + xf[7]*qf[7];
                    if (h == 0) sc0 += d; else if (h == 1) sc1 += d;
                    else if (h == 2) sc2 += d; else sc3 += d;
                }
            }
            // softmax-max skipped: |scores| << 1 at this weight scale (shift-invariant w)
            const float p0 = __expf(sc0), p1 = __expf(sc1), p2 = __expf(sc2), p3 = __expf(sc3);
            float4 pv; pv.x = p0; pv.y = p1; pv.z = p2; pv.w = p3;
            *(float4*)&s_p[n*4] = pv;
            atomicAdd(&s_P[0*8 + c], p0);
            atomicAdd(&s_P[1*8 + c], p1);
            atomicAdd(&s_P[2*8 + c], p2);
            atomicAdd(&s_P[3*8 + c], p3);
            atomicAdd(&s_cnt[c], 1.0f);
        }

        // ---- segment accumulation straight from C-fragments ----
        #pragma unroll
        for (int mb = 0; mb < 4; ++mb)
            #pragma unroll
            for (int r = 0; r < 4; ++r) {
                const int row = w*64 + mb*16 + (lane >> 4)*4 + r;
                const float4 p = *(const float4*)&s_p[row*4];
                const int coff = s_cl[row];
                #pragma unroll
                for (int eb = 0; eb < 4; ++eb) {
                    const float xsf = acc[mb][eb][r];
                    const int e = eb*16 + (lane & 15);
                    atomicAdd(&s_acc[0*512 + coff + e], p.x * xsf);
                    atomicAdd(&s_acc[1*512 + coff + e], p.y * xsf);
                    atomicAdd(&s_acc[2*512 + coff + e], p.z * xsf);
                    atomicAdd(&s_acc[3*512 + coff + e], p.w * xsf);
                    atomicAdd(&s_acc[4*512 + coff + e], xsf);
                }
            }
    }

    // ---- flush block partials to global acc ----
    __syncthreads();
    for (int i = tid; i < 2048; i += 256) {
        const int h = i >> 9, rr = i & 511, c = rr >> 6, e = rr & 63;
        atomicAdd(&gacc[ACC_SXW + (h*64 + e)*8 + c], s_acc[h*512 + c*64 + e]);
    }
    for (int i = tid; i < 512; i += 256) {
        const int c = i >> 6, e = i & 63;
        atomicAdd(&gacc[ACC_AXS + e*8 + c], s_acc[4*512 + c*64 + e]);
    }
    if (tid < 32) atomicAdd(&gacc[ACC_P + tid], s_P[tid]);
    if (tid < 8)  atomicAdd(&gacc[ACC_CNT + tid], s_cnt[tid]);
}

// ---------------- kernel C: class-level finalize -> fused[c][e] ----------------
__global__ __launch_bounds__(512) void kC(
    const float* __restrict__ sem_v, const float* __restrict__ sem_c,
    const float* __restrict__ Wqkv_v, const float* __restrict__ bqkv_v,
    const float* __restrict__ Wqkv_c, const float* __restrict__ bqkv_c,
    const float* __restrict__ Wo_v, const float* __restrict__ bo_v,
    const float* __restrict__ Wo_c, const float* __restrict__ bo_c,
    const float* __restrict__ Wr_v, const float* __restrict__ br_v,
    const float* __restrict__ Wr_c, const float* __restrict__ br_c,
    const float* __restrict__ Wg_v, const float* __restrict__ bg_v,
    const float* __restrict__ Wg_c, const float* __restrict__ bg_c,
    const float* __restrict__ gamma, const float* __restrict__ beta,
    float* __restrict__ ws)
{
    const int side = blockIdx.x;
    const float* sem  = side ? sem_c  : sem_v;
    const float* Wqkv = side ? Wqkv_c : Wqkv_v;
    const float* bqkv = side ? bqkv_c : bqkv_v;
    const float* Wo = side ? Wo_c : Wo_v;  const float* bo = side ? bo_c : bo_v;
    const float* Wr = side ? Wr_c : Wr_v;  const float* br = side ? br_c : br_v;
    const float* Wg = side ? Wg_c : Wg_v;  const float* bg = side ? bg_c : bg_v;
    const float* gacc = ws + (side ? OFF_ACC_C : OFF_ACC_V);
    float* fused = ws + (side ? OFF_FUSED_C : OFF_FUSED_V);
    const float* Wv = Wqkv + 2*E*E;
    const float* bv = bqkv + 2*E;

    const int tid = threadIdx.x;
    const int c = tid >> 6, e = tid & 63, h = e >> 4;

    __shared__ float s_a[NC][E];
    __shared__ float s_b[NC][E];
    __shared__ float s_old[NC][E];
    __shared__ float s_new[NC][E];

    const float Z = gacc[ACC_P + h*8 + c];
    float s = 0.0f;
    for (int j = 0; j < 64; ++j) s += gacc[ACC_SXW + (h*64 + j)*8 + c] * Wv[e*64 + j];
    s_a[c][e] = bv[e] + s / Z;
    __syncthreads();

    float s2 = bo[e];
    for (int j = 0; j < 64; ++j) s2 += s_a[c][j] * Wo[e*64 + j];
    s_b[c][e] = s2;
    const float cnt = gacc[ACC_CNT + c];
    const float oldv = gacc[ACC_AXS + e*8 + c] / fmaxf(cnt, 1.0f);
    s_old[c][e] = oldv;
    __syncthreads();

    float s3 = br[e];
    for (int j = 0; j < 64; ++j) s3 += sem[c*64 + j] * Wr[e*128 + j];
    for (int j = 0; j < 64; ++j) s3 += s_b[c][j]    * Wr[e*128 + 64 + j];
    s_new[c][e] = s3;
    __syncthreads();

    float s4 = bg[e];
    for (int j = 0; j < 64; ++j) s4 += s_old[c][j] * Wg[e*128 + j];
    for (int j = 0; j < 64; ++j) s4 += s_new[c][j] * Wg[e*128 + 64 + j];
    const float g = 1.0f / (1.0f + __expf(-s4));
    const float f = g * oldv + (1.0f - g) * s3;

    float sum = f;
    for (int m = 32; m >= 1; m >>= 1) sum += __shfl_xor(sum, m, 64);
    const float mu = sum * (1.0f/64.0f);
    const float d  = f - mu;
    float sq = d * d;
    for (int m = 32; m >= 1; m >>= 1) sq += __shfl_xor(sq, m, 64);
    const float var = sq * (1.0f/64.0f);
    fused[c*64 + e] = d * rsqrtf(var + 1e-5f) * gamma[e] + beta[e];
}

// ---------------- kernel D: out[n] = fused[cls[n]] * x[n] ----------------
__global__ __launch_bounds__(256) void kD(
    const float* __restrict__ xv, const float* __restrict__ xc,
    const int* __restrict__ clsv, const int* __restrict__ clsc,
    const float* __restrict__ ws, float* __restrict__ out)
{
    const int stride = gridDim.x * blockDim.x;
    const int TOT = 2 * N_NODES * 16;
    for (int i = blockIdx.x * blockDim.x + threadIdx.x; i < TOT; i += stride) {
        const int side  = i >= N_NODES * 16;
        const int local = side ? i - N_NODES * 16 : i;
        const int n = local >> 4;
        const int cc = side ? clsc[n] : clsv[n];
        const float* fu = ws + (side ? OFF_FUSED_C : OFF_FUSED_V);
        const float4 f  = reinterpret_cast<const float4*>(fu)[cc*16 + (local & 15)];
        const float* x  = side ? xc : xv;
        const float4 x4 = reinterpret_cast<const float4*>(x)[local];
        float4 o;
        o.x = f.x * x4.x; o.y = f.y * x4.y; o.z = f.z * x4.z; o.w = f.w * x4.w;
        reinterpret_cast<float4*>(out)[i] = o;
    }
}

extern "C" void kernel_launch(void* const* d_in, const int* in_sizes, int n_in,
                              void* d_out, int out_size, void* d_ws, size_t ws_size,
                              hipStream_t stream) {
    const float* v      = (const float*)d_in[0];
    const float* c      = (const float*)d_in[1];
    const float* v_sem  = (const float*)d_in[2];
    const float* c_sem  = (const float*)d_in[3];
    const int*   v_cls  = (const int*)d_in[4];
    const int*   c_cls  = (const int*)d_in[5];
    const float* Ws_v   = (const float*)d_in[6],  *bs_v   = (const float*)d_in[7];
    const float* Ws_c   = (const float*)d_in[8],  *bs_c   = (const float*)d_in[9];
    const float* Wqkv_v = (const float*)d_in[10], *bqkv_v = (const float*)d_in[11];
    const float* Wo_v   = (const float*)d_in[12], *bo_v   = (const float*)d_in[13];
    const float* Wqkv_c = (const float*)d_in[14], *bqkv_c = (const float*)d_in[15];
    const float* Wo_c   = (const float*)d_in[16], *bo_c   = (const float*)d_in[17];
    const float* Wr_v   = (const float*)d_in[18], *br_v   = (const float*)d_in[19];
    const float* Wr_c   = (const float*)d_in[20], *br_c   = (const float*)d_in[21];
    const float* Wg_v   = (const float*)d_in[22], *bg_v   = (const float*)d_in[23];
    const float* Wg_c   = (const float*)d_in[24], *bg_c   = (const float*)d_in[25];
    const float* gamma  = (const float*)d_in[26], *beta   = (const float*)d_in[27];
    float* ws  = (float*)d_ws;
    float* out = (float*)d_out;

    kQ<<<2, 512, 0, stream>>>(v_sem, c_sem, Wqkv_v, bqkv_v, Wqkv_c, bqkv_c, ws);
    kA<<<2*BPS2, 256, 0, stream>>>(v, c, v_cls, c_cls, Ws_v, bs_v, Ws_c, bs_c, ws);
    kC<<<2, 512, 0, stream>>>(v_sem, c_sem, Wqkv_v, bqkv_v, Wqkv_c, bqkv_c,
                              Wo_v, bo_v, Wo_c, bo_c, Wr_v, br_v, Wr_c, br_c,
                              Wg_v, bg_v, Wg_c, bg_c, gamma, beta, ws);
    kD<<<4096, 256, 0, stream>>>(v, c, v_cls, c_cls, ws, out);
}

// Round 3
// 333.485 us; speedup vs baseline: 5.9856x; 5.7457x over previous
//
#include <hip/hip_runtime.h>
#include <math.h>

#define N_NODES 524288
#define E 64
#define NC 8
#define TILE 128
#define BPS3 256                 // kA blocks per side
#define ITERS3 16                // 256 blocks * 16 tiles * 128 nodes = 524288

// ---- workspace layout (float offsets) ----
#define OFF_WQ_V    0      // WQ[hc][j]  hc=h*8+c  (2048)
#define OFF_SB_V    2048   // sbias[hc]            (32)
#define OFF_WQ_C    2080
#define OFF_SB_C    4128
#define OFF_ACC_V   4160   // 2600 floats
#define OFF_ACC_C   6760
#define OFF_FUSED_V 9360   // 512
#define OFF_FUSED_C 9872
// gacc internal layout:
#define ACC_SXW 0      // [(h*64+j)*8 + c]  (2048)  sum of p_h * xs_j per class
#define ACC_AXS 2048   // [j*8 + c]         (512)   sum of xs_j per class
#define ACC_P   2560   // [h*8 + c]         (32)    sum of p_h per class
#define ACC_CNT 2592   // [c]               (8)
#define ACC_TOTAL 2600

#define XSTR 136       // halfword stride for XT / P rows (16B-aligned)

typedef __attribute__((ext_vector_type(8))) short bf16x8;
typedef __attribute__((ext_vector_type(4))) float f32x4;

__device__ __forceinline__ unsigned short f2bf(float f) {
    union { float f; unsigned u; } v; v.f = f;
    return (unsigned short)((v.u + 0x7fffu + ((v.u >> 16) & 1u)) >> 16);  // RNE
}
__device__ __forceinline__ bf16x8 load8bf(const float* p) {
    float4 a = *(const float4*)p;
    float4 b = *(const float4*)(p + 4);
    bf16x8 r;
    r[0] = (short)f2bf(a.x); r[1] = (short)f2bf(a.y);
    r[2] = (short)f2bf(a.z); r[3] = (short)f2bf(a.w);
    r[4] = (short)f2bf(b.x); r[5] = (short)f2bf(b.y);
    r[6] = (short)f2bf(b.z); r[7] = (short)f2bf(b.w);
    return r;
}

// ---------------- kernel Q: fold Wq,Wk,Ws into WQ/sbias; zero accumulators ----------------
__global__ __launch_bounds__(512) void kQ(
    const float* __restrict__ sem_v, const float* __restrict__ sem_c,
    const float* __restrict__ Wqkv_v, const float* __restrict__ bqkv_v,
    const float* __restrict__ Wqkv_c, const float* __restrict__ bqkv_c,
    const float* __restrict__ Ws_v, const float* __restrict__ bs_v,
    const float* __restrict__ Ws_c, const float* __restrict__ bs_c,
    float* __restrict__ ws)
{
    const int side = blockIdx.x;
    const float* sem  = side ? sem_c  : sem_v;
    const float* Wqkv = side ? Wqkv_c : Wqkv_v;
    const float* bqkv = side ? bqkv_c : bqkv_v;
    const float* Ws   = side ? Ws_c   : Ws_v;
    const float* bs   = side ? bs_c   : bs_v;
    float* WQo  = ws + (side ? OFF_WQ_C : OFF_WQ_V);
    float* sbo  = ws + (side ? OFF_SB_C : OFF_SB_V);
    float* gacc = ws + (side ? OFF_ACC_C : OFF_ACC_V);
    const int tid = threadIdx.x;

    for (int i = tid; i < ACC_TOTAL; i += 512) gacc[i] = 0.0f;

    __shared__ float s_q[NC][E];
    __shared__ float s_qk[32][E];   // [hc][e]
    {   // q[c][e] = (bq[e] + sem[c]·Wq[e]) * (1/sqrt(16))
        const int c = tid >> 6, e = tid & 63;
        float a = bqkv[e];
        for (int j = 0; j < E; ++j) a += sem[c*E + j] * Wqkv[e*E + j];
        s_q[c][e] = a * 0.25f;
    }
    __syncthreads();

    const float* Wk = Wqkv + E*E;
    const float* bk = bqkv + E;
    for (int r = 0; r < 4; ++r) {
        int idx = r*512 + tid;             // idx = hc*64 + e
        int hc = idx >> 6, e = idx & 63;
        int h = hc >> 3, c = hc & 7;
        float a = 0.0f;
        for (int d = 0; d < 16; ++d) a += Wk[(h*16+d)*E + e] * s_q[c][h*16+d];
        s_qk[hc][e] = a;
    }
    __syncthreads();

    // WQ[hc][j] = sum_e qk[hc][e] * Ws[e][j]
    for (int r = 0; r < 4; ++r) {
        int idx = r*512 + tid;
        int hc = idx >> 6, j = idx & 63;
        float a = 0.0f;
        for (int e = 0; e < 64; ++e) a += s_qk[hc][e] * Ws[e*64 + j];
        WQo[idx] = a;
    }
    // sbias[hc] = qb[hc] + sum_e qk[hc][e]*bs[e]
    if (tid < 32) {
        int hc = tid, h = hc >> 3, c = hc & 7;
        float a = 0.0f;
        for (int d = 0; d < 16; ++d) a += bk[h*16+d] * s_q[c][h*16+d];
        for (int e = 0; e < 64; ++e) a += s_qk[hc][e] * bs[e];
        sbo[tid] = a;
    }
}

// ---------------- kernel A: double-MFMA segment attention, zero hot-loop atomics ----------------
__global__ __launch_bounds__(256, 2) void kA(
    const float* __restrict__ xv, const float* __restrict__ xc,
    const int* __restrict__ clsv, const int* __restrict__ clsc,
    const float* __restrict__ Ws_v, const float* __restrict__ bs_v,
    const float* __restrict__ Ws_c, const float* __restrict__ bs_c,
    float* __restrict__ ws)
{
    const int bid  = blockIdx.x;
    const int side = bid >> 8;
    const float* x    = side ? xc   : xv;
    const int*   cls  = side ? clsc : clsv;
    const float* Ws   = side ? Ws_c : Ws_v;
    const float* bs   = side ? bs_c : bs_v;
    const float* WQ   = ws + (side ? OFF_WQ_C : OFF_WQ_V);
    const float* sbia = ws + (side ? OFF_SB_C : OFF_SB_V);
    float* gacc = ws + (side ? OFF_ACC_C : OFF_ACC_V);
    const int tid  = threadIdx.x;
    const int w    = tid >> 6;
    const int lane = tid & 63;
    const int li   = lane & 15, lg = lane >> 4;

    __shared__ unsigned short XT[80 * XSTR];   // xs^T bf16: rows 0..63 = e, 64 = ones, 65..79 = 0
    __shared__ unsigned short P[48 * XSTR];    // P bf16: rows 0..31 = (h,c) p, 32..39 = indicator, 40..47 = 0
    __shared__ float SC[TILE * 33];            // scores f32 [node][hc]
    __shared__ float ACCR[48 * 84];            // block-level reduce staging (flush only)

    // ---- A-fragments: rows 0..63 = Ws (e), rows 64..95 = WQ (hc). Held in regs all kernel.
    bf16x8 AF[6][2];
    #pragma unroll
    for (int mb = 0; mb < 6; ++mb) {
        const int m = mb*16 + li;
        const float* src = (mb < 4) ? (Ws + m*64) : (WQ + (m - 64)*64);
        #pragma unroll
        for (int kb = 0; kb < 2; ++kb)
            AF[mb][kb] = load8bf(src + kb*32 + lg*8);
    }
    // per-thread bias registers
    float bsr[16], sbr[8];
    #pragma unroll
    for (int mb = 0; mb < 4; ++mb)
        #pragma unroll
        for (int r = 0; r < 4; ++r) bsr[mb*4+r] = bs[mb*16 + lg*4 + r];
    #pragma unroll
    for (int sb = 0; sb < 2; ++sb)
        #pragma unroll
        for (int r = 0; r < 4; ++r) sbr[sb*4+r] = sbia[sb*16 + lg*4 + r];

    // constant LDS rows
    for (int i = tid; i < 16*XSTR; i += 256) XT[64*XSTR + i] = (i < XSTR) ? 0x3F80 : 0;
    for (int i = tid; i < 8*XSTR; i += 256) P[40*XSTR + i] = 0;
    __syncthreads();

    f32x4 acc2[3][5];
    #pragma unroll
    for (int a = 0; a < 3; ++a)
        #pragma unroll
        for (int b = 0; b < 5; ++b) acc2[a][b] = (f32x4){0.f,0.f,0.f,0.f};

    const int bloc = bid & (BPS3 - 1);
    for (int t = 0; t < ITERS3; ++t) {
        const int tilebase = (bloc * ITERS3 + t) * TILE;

        // ---- MFMA1: [Ws;WQ] @ x^T  -> xs^T (to XT) and scores (to SC) ----
        #pragma unroll
        for (int nb = 0; nb < 2; ++nb) {
            const int nt = w*32 + nb*16 + li;           // within-tile node (B col)
            const float* xp = x + (tilebase + nt)*64 + lg*8;
            bf16x8 B0 = load8bf(xp);
            bf16x8 B1 = load8bf(xp + 32);
            f32x4 Cf[6];
            #pragma unroll
            for (int mb = 0; mb < 6; ++mb) {
                f32x4 c0 = {0.f,0.f,0.f,0.f};
                c0 = __builtin_amdgcn_mfma_f32_16x16x32_bf16(AF[mb][0], B0, c0, 0, 0, 0);
                c0 = __builtin_amdgcn_mfma_f32_16x16x32_bf16(AF[mb][1], B1, c0, 0, 0, 0);
                Cf[mb] = c0;
            }
            // xs^T rows: e = mb*16 + lg*4 + r, col = nt
            #pragma unroll
            for (int mb = 0; mb < 4; ++mb)
                #pragma unroll
                for (int r = 0; r < 4; ++r)
                    XT[(mb*16 + lg*4 + r)*XSTR + nt] = f2bf(Cf[mb][r] + bsr[mb*4+r]);
            // scores: hc = sb*16 + lg*4 + r
            #pragma unroll
            for (int sb = 0; sb < 2; ++sb)
                #pragma unroll
                for (int r = 0; r < 4; ++r)
                    SC[nt*33 + sb*16 + lg*4 + r] = Cf[4+sb][r] + sbr[sb*4+r];
        }
        // zero P rows 0..39 for this wave's node columns
        {
            const uint4 z4 = {0u,0u,0u,0u};
            for (int i = lane; i < 160; i += 64) {
                const int row = i >> 2, cg = i & 3;
                *(uint4*)&P[row*XSTR + w*32 + cg*8] = z4;
            }
        }
        __syncthreads();

        // ---- p = exp(score) scatter into P (2 heads per thread) ----
        {
            const int nt = tid & 127, hp = tid >> 7;
            const int myc = cls[tilebase + nt];
            const float sa = SC[nt*33 + (hp*2    )*8 + myc];
            const float sb2= SC[nt*33 + (hp*2 + 1)*8 + myc];
            // softmax-max skipped: |scores| << 1 at this weight scale (shift-invariant w)
            P[((hp*2    )*8 + myc)*XSTR + nt] = f2bf(__expf(sa));
            P[((hp*2 + 1)*8 + myc)*XSTR + nt] = f2bf(__expf(sb2));
            if (hp == 0) P[(32 + myc)*XSTR + nt] = 0x3F80;   // indicator row
        }
        __syncthreads();

        // ---- MFMA2: ACC[48 hc][80 e] += P @ [xs | 1]; wave w handles k = its own 32 nodes ----
        {
            const int kbase = w*32 + lg*8;
            bf16x8 PA[3], XB[5];
            #pragma unroll
            for (int a = 0; a < 3; ++a) PA[a] = *(const bf16x8*)&P[(a*16 + li)*XSTR + kbase];
            #pragma unroll
            for (int b = 0; b < 5; ++b) XB[b] = *(const bf16x8*)&XT[(b*16 + li)*XSTR + kbase];
            #pragma unroll
            for (int a = 0; a < 3; ++a)
                #pragma unroll
                for (int b = 0; b < 5; ++b)
                    acc2[a][b] = __builtin_amdgcn_mfma_f32_16x16x32_bf16(PA[a], XB[b], acc2[a][b], 0, 0, 0);
        }
    }

    // ---- block-level reduce of acc2 across waves, then one global flush ----
    __syncthreads();
    for (int i = tid; i < 48*84; i += 256) ACCR[i] = 0.0f;
    __syncthreads();
    #pragma unroll
    for (int a = 0; a < 3; ++a)
        #pragma unroll
        for (int b = 0; b < 5; ++b)
            #pragma unroll
            for (int r = 0; r < 4; ++r)
                atomicAdd(&ACCR[(a*16 + lg*4 + r)*84 + b*16 + li], acc2[a][b][r]);
    __syncthreads();
    for (int i = tid; i < 2600; i += 256) {
        const int hc = i / 65, j = i - hc*65;
        const float vv = ACCR[hc*84 + j];
        int dst;
        if (hc < 32) dst = (j < 64) ? (ACC_SXW + ((hc>>3)*64 + j)*8 + (hc&7)) : (ACC_P + hc);
        else { const int c2 = hc - 32; dst = (j < 64) ? (ACC_AXS + j*8 + c2) : (ACC_CNT + c2); }
        atomicAdd(&gacc[dst], vv);
    }
}

// ---------------- kernel C: class-level finalize -> fused[c][e] ----------------
__global__ __launch_bounds__(512) void kC(
    const float* __restrict__ sem_v, const float* __restrict__ sem_c,
    const float* __restrict__ Wqkv_v, const float* __restrict__ bqkv_v,
    const float* __restrict__ Wqkv_c, const float* __restrict__ bqkv_c,
    const float* __restrict__ Wo_v, const float* __restrict__ bo_v,
    const float* __restrict__ Wo_c, const float* __restrict__ bo_c,
    const float* __restrict__ Wr_v, const float* __restrict__ br_v,
    const float* __restrict__ Wr_c, const float* __restrict__ br_c,
    const float* __restrict__ Wg_v, const float* __restrict__ bg_v,
    const float* __restrict__ Wg_c, const float* __restrict__ bg_c,
    const float* __restrict__ gamma, const float* __restrict__ beta,
    float* __restrict__ ws)
{
    const int side = blockIdx.x;
    const float* sem  = side ? sem_c  : sem_v;
    const float* Wqkv = side ? Wqkv_c : Wqkv_v;
    const float* bqkv = side ? bqkv_c : bqkv_v;
    const float* Wo = side ? Wo_c : Wo_v;  const float* bo = side ? bo_c : bo_v;
    const float* Wr = side ? Wr_c : Wr_v;  const float* br = side ? br_c : br_v;
    const float* Wg = side ? Wg_c : Wg_v;  const float* bg = side ? bg_c : bg_v;
    const float* gacc = ws + (side ? OFF_ACC_C : OFF_ACC_V);
    float* fused = ws + (side ? OFF_FUSED_C : OFF_FUSED_V);
    const float* Wv = Wqkv + 2*E*E;
    const float* bv = bqkv + 2*E;

    const int tid = threadIdx.x;
    const int c = tid >> 6, e = tid & 63, h = e >> 4;

    __shared__ float s_a[NC][E];
    __shared__ float s_b[NC][E];
    __shared__ float s_old[NC][E];
    __shared__ float s_new[NC][E];

    const float Z = gacc[ACC_P + h*8 + c];
    float s = 0.0f;
    for (int j = 0; j < 64; ++j) s += gacc[ACC_SXW + (h*64 + j)*8 + c] * Wv[e*64 + j];
    s_a[c][e] = bv[e] + s / Z;
    __syncthreads();

    float s2 = bo[e];
    for (int j = 0; j < 64; ++j) s2 += s_a[c][j] * Wo[e*64 + j];
    s_b[c][e] = s2;
    const float cnt = gacc[ACC_CNT + c];
    const float oldv = gacc[ACC_AXS + e*8 + c] / fmaxf(cnt, 1.0f);
    s_old[c][e] = oldv;
    __syncthreads();

    float s3 = br[e];
    for (int j = 0; j < 64; ++j) s3 += sem[c*64 + j] * Wr[e*128 + j];
    for (int j = 0; j < 64; ++j) s3 += s_b[c][j]    * Wr[e*128 + 64 + j];
    s_new[c][e] = s3;
    __syncthreads();

    float s4 = bg[e];
    for (int j = 0; j < 64; ++j) s4 += s_old[c][j] * Wg[e*128 + j];
    for (int j = 0; j < 64; ++j) s4 += s_new[c][j] * Wg[e*128 + 64 + j];
    const float g = 1.0f / (1.0f + __expf(-s4));
    const float f = g * oldv + (1.0f - g) * s3;

    float sum = f;
    for (int m = 32; m >= 1; m >>= 1) sum += __shfl_xor(sum, m, 64);
    const float mu = sum * (1.0f/64.0f);
    const float d  = f - mu;
    float sq = d * d;
    for (int m = 32; m >= 1; m >>= 1) sq += __shfl_xor(sq, m, 64);
    const float var = sq * (1.0f/64.0f);
    fused[c*64 + e] = d * rsqrtf(var + 1e-5f) * gamma[e] + beta[e];
}

// ---------------- kernel D: out[n] = fused[cls[n]] * x[n] ----------------
__global__ __launch_bounds__(256) void kD(
    const float* __restrict__ xv, const float* __restrict__ xc,
    const int* __restrict__ clsv, const int* __restrict__ clsc,
    const float* __restrict__ ws, float* __restrict__ out)
{
    const int stride = gridDim.x * blockDim.x;
    const int TOT = 2 * N_NODES * 16;
    for (int i = blockIdx.x * blockDim.x + threadIdx.x; i < TOT; i += stride) {
        const int side  = i >= N_NODES * 16;
        const int local = side ? i - N_NODES * 16 : i;
        const int n = local >> 4;
        const int cc = side ? clsc[n] : clsv[n];
        const float* fu = ws + (side ? OFF_FUSED_C : OFF_FUSED_V);
        const float4 f  = reinterpret_cast<const float4*>(fu)[cc*16 + (local & 15)];
        const float* x  = side ? xc : xv;
        const float4 x4 = reinterpret_cast<const float4*>(x)[local];
        float4 o;
        o.x = f.x * x4.x; o.y = f.y * x4.y; o.z = f.z * x4.z; o.w = f.w * x4.w;
        reinterpret_cast<float4*>(out)[i] = o;
    }
}

extern "C" void kernel_launch(void* const* d_in, const int* in_sizes, int n_in,
                              void* d_out, int out_size, void* d_ws, size_t ws_size,
                              hipStream_t stream) {
    const float* v      = (const float*)d_in[0];
    const float* c      = (const float*)d_in[1];
    const float* v_sem  = (const float*)d_in[2];
    const float* c_sem  = (const float*)d_in[3];
    const int*   v_cls  = (const int*)d_in[4];
    const int*   c_cls  = (const int*)d_in[5];
    const float* Ws_v   = (const float*)d_in[6],  *bs_v   = (const float*)d_in[7];
    const float* Ws_c   = (const float*)d_in[8],  *bs_c   = (const float*)d_in[9];
    const float* Wqkv_v = (const float*)d_in[10], *bqkv_v = (const float*)d_in[11];
    const float* Wo_v   = (const float*)d_in[12], *bo_v   = (const float*)d_in[13];
    const float* Wqkv_c = (const float*)d_in[14], *bqkv_c = (const float*)d_in[15];
    const float* Wo_c   = (const float*)d_in[16], *bo_c   = (const float*)d_in[17];
    const float* Wr_v   = (const float*)d_in[18], *br_v   = (const float*)d_in[19];
    const float* Wr_c   = (const float*)d_in[20], *br_c   = (const float*)d_in[21];
    const float* Wg_v   = (const float*)d_in[22], *bg_v   = (const float*)d_in[23];
    const float* Wg_c   = (const float*)d_in[24], *bg_c   = (const float*)d_in[25];
    const float* gamma  = (const float*)d_in[26], *beta   = (const float*)d_in[27];
    float* ws  = (float*)d_ws;
    float* out = (float*)d_out;

    kQ<<<2, 512, 0, stream>>>(v_sem, c_sem, Wqkv_v, bqkv_v, Wqkv_c, bqkv_c,
                              Ws_v, bs_v, Ws_c, bs_c, ws);
    kA<<<2*BPS3, 256, 0, stream>>>(v, c, v_cls, c_cls, Ws_v, bs_v, Ws_c, bs_c, ws);
    kC<<<2, 512, 0, stream>>>(v_sem, c_sem, Wqkv_v, bqkv_v, Wqkv_c, bqkv_c,
                              Wo_v, bo_v, Wo_c, bo_c, Wr_v, br_v, Wr_c, br_c,
                              Wg_v, bg_v, Wg_c, bg_c, gamma, beta, ws);
    kD<<<4096, 256, 0, stream>>>(v, c, v_cls, c_cls, ws, out);
}

// Round 6
// 327.017 us; speedup vs baseline: 6.1040x; 1.0198x over previous
//
#include <hip/hip_runtime.h>
#include <math.h>

#define N_NODES 524288
#define E 64
#define NC 8
#define TILE 128
#define BPS3 256                 // kA blocks per side
#define ITERS3 16                // 256 blocks * 16 tiles * 128 nodes = 524288

// ---- workspace layout (float offsets) ----
#define OFF_WQ_V    0      // WQ[hc][j]  hc=h*8+c  (2048)
#define OFF_SB_V    2048   // sbias[hc]            (32)
#define OFF_WQ_C    2080
#define OFF_SB_C    4128
#define OFF_ACC_V   4160   // 2600 floats
#define OFF_ACC_C   6760
#define OFF_FUSED_V 9360   // 512
#define OFF_FUSED_C 9872
// gacc internal layout:
#define ACC_SXW 0      // [(h*64+j)*8 + c]  (2048)  sum of p_h * xs_j per class
#define ACC_AXS 2048   // [j*8 + c]         (512)   sum of xs_j per class
#define ACC_P   2560   // [h*8 + c]         (32)    sum of p_h per class
#define ACC_CNT 2592   // [c]               (8)
#define ACC_TOTAL 2600

#define XSTR 136       // halfword stride for XT / P rows (272B, 16B-aligned, conflict-free)

typedef __attribute__((ext_vector_type(8))) short bf16x8;
typedef __attribute__((ext_vector_type(4))) float f32x4;

__device__ __forceinline__ unsigned short f2bf(float f) {
    union { float f; unsigned u; } v; v.f = f;
    return (unsigned short)((v.u + 0x7fffu + ((v.u >> 16) & 1u)) >> 16);  // RNE
}
__device__ __forceinline__ bf16x8 pack8s(float4 a, float4 b) {
    bf16x8 r;
    r[0] = (short)f2bf(a.x); r[1] = (short)f2bf(a.y);
    r[2] = (short)f2bf(a.z); r[3] = (short)f2bf(a.w);
    r[4] = (short)f2bf(b.x); r[5] = (short)f2bf(b.y);
    r[6] = (short)f2bf(b.z); r[7] = (short)f2bf(b.w);
    return r;
}
__device__ __forceinline__ bf16x8 load8bf(const float* p) {
    return pack8s(*(const float4*)p, *(const float4*)(p + 4));
}

// ---------------- kernel Q: fold Wq,Wk,Ws into WQ/sbias; zero accumulators ----------------
__global__ __launch_bounds__(512) void kQ(
    const float* __restrict__ sem_v, const float* __restrict__ sem_c,
    const float* __restrict__ Wqkv_v, const float* __restrict__ bqkv_v,
    const float* __restrict__ Wqkv_c, const float* __restrict__ bqkv_c,
    const float* __restrict__ Ws_v, const float* __restrict__ bs_v,
    const float* __restrict__ Ws_c, const float* __restrict__ bs_c,
    float* __restrict__ ws)
{
    const int side = blockIdx.x;
    const float* sem  = side ? sem_c  : sem_v;
    const float* Wqkv = side ? Wqkv_c : Wqkv_v;
    const float* bqkv = side ? bqkv_c : bqkv_v;
    const float* Ws   = side ? Ws_c   : Ws_v;
    const float* bs   = side ? bs_c   : bs_v;
    float* WQo  = ws + (side ? OFF_WQ_C : OFF_WQ_V);
    float* sbo  = ws + (side ? OFF_SB_C : OFF_SB_V);
    float* gacc = ws + (side ? OFF_ACC_C : OFF_ACC_V);
    const int tid = threadIdx.x;

    for (int i = tid; i < ACC_TOTAL; i += 512) gacc[i] = 0.0f;

    __shared__ float s_q[NC][E];
    __shared__ float s_qk[32][E];   // [hc][e]
    {   // q[c][e] = (bq[e] + sem[c]·Wq[e]) * (1/sqrt(16))
        const int c = tid >> 6, e = tid & 63;
        float a = bqkv[e];
        for (int j = 0; j < E; ++j) a += sem[c*E + j] * Wqkv[e*E + j];
        s_q[c][e] = a * 0.25f;
    }
    __syncthreads();

    const float* Wk = Wqkv + E*E;
    const float* bk = bqkv + E;
    for (int r = 0; r < 4; ++r) {
        int idx = r*512 + tid;             // idx = hc*64 + e
        int hc = idx >> 6, e = idx & 63;
        int h = hc >> 3, c = hc & 7;
        float a = 0.0f;
        for (int d = 0; d < 16; ++d) a += Wk[(h*16+d)*E + e] * s_q[c][h*16+d];
        s_qk[hc][e] = a;
    }
    __syncthreads();

    // WQ[hc][j] = sum_e qk[hc][e] * Ws[e][j]
    for (int r = 0; r < 4; ++r) {
        int idx = r*512 + tid;
        int hc = idx >> 6, j = idx & 63;
        float a = 0.0f;
        for (int e = 0; e < 64; ++e) a += s_qk[hc][e] * Ws[e*64 + j];
        WQo[idx] = a;
    }
    // sbias[hc] = qb[hc] + sum_e qk[hc][e]*bs[e]
    if (tid < 32) {
        int hc = tid, h = hc >> 3, c = hc & 7;
        float a = 0.0f;
        for (int d = 0; d < 16; ++d) a += bk[h*16+d] * s_q[c][h*16+d];
        for (int e = 0; e < 64; ++e) a += s_qk[hc][e] * bs[e];
        sbo[tid] = a;
    }
}

// ---------------- kernel A: double-MFMA segment attention (R3 structure + prefetch + LDS diet) ----------------
__global__ __launch_bounds__(256, 2) void kA(
    const float* __restrict__ xv, const float* __restrict__ xc,
    const int* __restrict__ clsv, const int* __restrict__ clsc,
    const float* __restrict__ Ws_v, const float* __restrict__ bs_v,
    const float* __restrict__ Ws_c, const float* __restrict__ bs_c,
    float* __restrict__ ws)
{
    const int bid  = blockIdx.x;
    const int side = bid >> 8;
    const float* x    = side ? xc   : xv;
    const int*   cls  = side ? clsc : clsv;
    const float* Ws   = side ? Ws_c : Ws_v;
    const float* bs   = side ? bs_c : bs_v;
    const float* WQ   = ws + (side ? OFF_WQ_C : OFF_WQ_V);
    const float* sbia = ws + (side ? OFF_SB_C : OFF_SB_V);
    float* gacc = ws + (side ? OFF_ACC_C : OFF_ACC_V);
    const int tid  = threadIdx.x;
    const int w    = tid >> 6;
    const int lane = tid & 63;
    const int li   = lane & 15, lg = lane >> 4;

    // LDS: XT 64x136 bf16 (17408 B) | P 48x136 bf16 (13056 B) | SC 128x33 f32 (16896 B) = 47360 B
    // ACCR (48x84 f32 = 16128 B) aliases XT; only touched after the post-loop __syncthreads().
    __shared__ __align__(16) unsigned char smem[47360];
    unsigned short* XT = (unsigned short*)(smem);
    unsigned short* P  = (unsigned short*)(smem + 17408);
    float*          SC = (float*)(smem + 30464);
    float*        ACCR = (float*)(smem);

    // ---- A-fragments: rows 0..63 = Ws (e), rows 64..95 = WQ (hc). Held in regs all kernel.
    bf16x8 AF[6][2];
    #pragma unroll
    for (int mb = 0; mb < 6; ++mb) {
        const int m = mb*16 + li;
        const float* src = (mb < 4) ? (Ws + m*64) : (WQ + (m - 64)*64);
        #pragma unroll
        for (int kb = 0; kb < 2; ++kb)
            AF[mb][kb] = load8bf(src + kb*32 + lg*8);
    }
    // per-thread bias registers (row-indexed: C/D row = lg*4+r)
    float bsr[16], sbr[8];
    #pragma unroll
    for (int mb = 0; mb < 4; ++mb)
        #pragma unroll
        for (int r = 0; r < 4; ++r) bsr[mb*4+r] = bs[mb*16 + lg*4 + r];
    #pragma unroll
    for (int sb = 0; sb < 2; ++sb)
        #pragma unroll
        for (int r = 0; r < 4; ++r) sbr[sb*4+r] = sbia[sb*16 + lg*4 + r];

    // constant "ones" B-block for MFMA2 (equiv. to R3's XT rows 64..79: col 64 = 1, rest 0)
    bf16x8 XB4;
    {
        const short v = (li == 0) ? (short)0x3F80 : (short)0;
        #pragma unroll
        for (int j = 0; j < 8; ++j) XB4[j] = v;
    }

    // P padding rows 40..47 stay zero forever (cooperative init, then barrier)
    for (int i = tid; i < 8*XSTR; i += 256) P[40*XSTR + i] = 0;
    __syncthreads();

    f32x4 acc2[3][5];
    #pragma unroll
    for (int a = 0; a < 3; ++a)
        #pragma unroll
        for (int b = 0; b < 5; ++b) acc2[a][b] = (f32x4){0.f,0.f,0.f,0.f};

    const int bloc = bid & (BPS3 - 1);

    // ---- depth-1 register prefetch of the x-tile + class ----
    float4 pf[8];
    int pcls;
    {
        const int tb = (bloc * ITERS3) * TILE;
        #pragma unroll
        for (int nb = 0; nb < 2; ++nb) {
            const int nt = w*32 + nb*16 + li;
            const float* xp = x + (size_t)(tb + nt)*64 + lg*8;
            pf[nb*4+0] = *(const float4*)xp;
            pf[nb*4+1] = *(const float4*)(xp + 4);
            pf[nb*4+2] = *(const float4*)(xp + 32);
            pf[nb*4+3] = *(const float4*)(xp + 36);
        }
        pcls = cls[tb + (tid & 127)];
    }

    for (int t = 0; t < ITERS3; ++t) {
        // consume prefetched tile into bf16 fragments
        bf16x8 B00 = pack8s(pf[0], pf[1]);
        bf16x8 B01 = pack8s(pf[2], pf[3]);
        bf16x8 B10 = pack8s(pf[4], pf[5]);
        bf16x8 B11 = pack8s(pf[6], pf[7]);
        const int myc = pcls;

        // issue next tile's loads now (consumed next iteration)
        if (t + 1 < ITERS3) {
            const int tb = (bloc * ITERS3 + t + 1) * TILE;
            #pragma unroll
            for (int nb = 0; nb < 2; ++nb) {
                const int nt = w*32 + nb*16 + li;
                const float* xp = x + (size_t)(tb + nt)*64 + lg*8;
                pf[nb*4+0] = *(const float4*)xp;
                pf[nb*4+1] = *(const float4*)(xp + 4);
                pf[nb*4+2] = *(const float4*)(xp + 32);
                pf[nb*4+3] = *(const float4*)(xp + 36);
            }
            pcls = cls[tb + (tid & 127)];
        }

        // ---- MFMA1: [Ws;WQ] @ x^T -> xs^T (to XT, bf16) and scores (to SC, f32) ----
        #pragma unroll
        for (int nb = 0; nb < 2; ++nb) {
            const int nt = w*32 + nb*16 + li;
            const bf16x8 Bk0 = nb ? B10 : B00;
            const bf16x8 Bk1 = nb ? B11 : B01;
            f32x4 Cf[6];
            #pragma unroll
            for (int mb = 0; mb < 6; ++mb) {
                f32x4 c0 = {0.f, 0.f, 0.f, 0.f};
                c0 = __builtin_amdgcn_mfma_f32_16x16x32_bf16(AF[mb][0], Bk0, c0, 0, 0, 0);
                c0 = __builtin_amdgcn_mfma_f32_16x16x32_bf16(AF[mb][1], Bk1, c0, 0, 0, 0);
                Cf[mb] = c0;
            }
            // xs^T rows: e = mb*16 + lg*4 + r, col = nt
            #pragma unroll
            for (int mb = 0; mb < 4; ++mb)
                #pragma unroll
                for (int r = 0; r < 4; ++r)
                    XT[(mb*16 + lg*4 + r)*XSTR + nt] = f2bf(Cf[mb][r] + bsr[mb*4+r]);
            // scores: hc = sb*16 + lg*4 + r
            #pragma unroll
            for (int sb = 0; sb < 2; ++sb)
                #pragma unroll
                for (int r = 0; r < 4; ++r)
                    SC[nt*33 + sb*16 + lg*4 + r] = Cf[4+sb][r] + sbr[sb*4+r];
        }
        // zero this wave's P column strip (rows 0..39)
        {
            const uint4 z4 = {0u,0u,0u,0u};
            for (int i = lane; i < 160; i += 64) {
                const int row = i >> 2, cg = i & 3;
                *(uint4*)&P[row*XSTR + w*32 + cg*8] = z4;
            }
        }
        __syncthreads();

        // ---- p = exp(score) scatter into P (2 heads per thread; cross-wave, barrier-protected) ----
        {
            const int nt = tid & 127, hp = tid >> 7;
            const float sa  = SC[nt*33 + (hp*2    )*8 + myc];
            const float sb2 = SC[nt*33 + (hp*2 + 1)*8 + myc];
            // softmax-max skipped: |scores| << 1 at this weight scale (shift-invariant w)
            P[((hp*2    )*8 + myc)*XSTR + nt] = f2bf(__expf(sa));
            P[((hp*2 + 1)*8 + myc)*XSTR + nt] = f2bf(__expf(sb2));
            if (hp == 0) P[(32 + myc)*XSTR + nt] = 0x3F80;   // indicator row
        }
        __syncthreads();

        // ---- MFMA2: ACC[48 hc][80 e] += P @ [xs | 1]; wave w covers its own 32-node k-range ----
        {
            const int kbase = w*32 + lg*8;
            bf16x8 PA0 = *(const bf16x8*)&P[(0*16 + li)*XSTR + kbase];
            bf16x8 PA1 = *(const bf16x8*)&P[(1*16 + li)*XSTR + kbase];
            bf16x8 PA2 = *(const bf16x8*)&P[(2*16 + li)*XSTR + kbase];
            #pragma unroll
            for (int b = 0; b < 4; ++b) {
                bf16x8 XB = *(const bf16x8*)&XT[(b*16 + li)*XSTR + kbase];
                acc2[0][b] = __builtin_amdgcn_mfma_f32_16x16x32_bf16(PA0, XB, acc2[0][b], 0, 0, 0);
                acc2[1][b] = __builtin_amdgcn_mfma_f32_16x16x32_bf16(PA1, XB, acc2[1][b], 0, 0, 0);
                acc2[2][b] = __builtin_amdgcn_mfma_f32_16x16x32_bf16(PA2, XB, acc2[2][b], 0, 0, 0);
            }
            acc2[0][4] = __builtin_amdgcn_mfma_f32_16x16x32_bf16(PA0, XB4, acc2[0][4], 0, 0, 0);
            acc2[1][4] = __builtin_amdgcn_mfma_f32_16x16x32_bf16(PA1, XB4, acc2[1][4], 0, 0, 0);
            acc2[2][4] = __builtin_amdgcn_mfma_f32_16x16x32_bf16(PA2, XB4, acc2[2][4], 0, 0, 0);
        }
    }

    // ---- block-level reduce of acc2 across waves, then one global flush ----
    __syncthreads();
    for (int i = tid; i < 48*84; i += 256) ACCR[i] = 0.0f;
    __syncthreads();
    #pragma unroll
    for (int a = 0; a < 3; ++a)
        #pragma unroll
        for (int b = 0; b < 5; ++b)
            #pragma unroll
            for (int r = 0; r < 4; ++r)
                atomicAdd(&ACCR[(a*16 + lg*4 + r)*84 + b*16 + li], acc2[a][b][r]);
    __syncthreads();
    for (int i = tid; i < 2600; i += 256) {
        const int hc = i / 65, j = i - hc*65;
        const float vv = ACCR[hc*84 + j];
        int dst;
        if (hc < 32) dst = (j < 64) ? (ACC_SXW + ((hc>>3)*64 + j)*8 + (hc&7)) : (ACC_P + hc);
        else { const int c2 = hc - 32; dst = (j < 64) ? (ACC_AXS + j*8 + c2) : (ACC_CNT + c2); }
        atomicAdd(&gacc[dst], vv);
    }
}

// ---------------- kernel C: class-level finalize -> fused[c][e] ----------------
__global__ __launch_bounds__(512) void kC(
    const float* __restrict__ sem_v, const float* __restrict__ sem_c,
    const float* __restrict__ Wqkv_v, const float* __restrict__ bqkv_v,
    const float* __restrict__ Wqkv_c, const float* __restrict__ bqkv_c,
    const float* __restrict__ Wo_v, const float* __restrict__ bo_v,
    const float* __restrict__ Wo_c, const float* __restrict__ bo_c,
    const float* __restrict__ Wr_v, const float* __restrict__ br_v,
    const float* __restrict__ Wr_c, const float* __restrict__ br_c,
    const float* __restrict__ Wg_v, const float* __restrict__ bg_v,
    const float* __restrict__ Wg_c, const float* __restrict__ bg_c,
    const float* __restrict__ gamma, const float* __restrict__ beta,
    float* __restrict__ ws)
{
    const int side = blockIdx.x;
    const float* sem  = side ? sem_c  : sem_v;
    const float* Wqkv = side ? Wqkv_c : Wqkv_v;
    const float* bqkv = side ? bqkv_c : bqkv_v;
    const float* Wo = side ? Wo_c : Wo_v;  const float* bo = side ? bo_c : bo_v;
    const float* Wr = side ? Wr_c : Wr_v;  const float* br = side ? br_c : br_v;
    const float* Wg = side ? Wg_c : Wg_v;  const float* bg = side ? bg_c : bg_v;
    const float* gacc = ws + (side ? OFF_ACC_C : OFF_ACC_V);
    float* fused = ws + (side ? OFF_FUSED_C : OFF_FUSED_V);
    const float* Wv = Wqkv + 2*E*E;
    const float* bv = bqkv + 2*E;

    const int tid = threadIdx.x;
    const int c = tid >> 6, e = tid & 63, h = e >> 4;

    __shared__ float s_a[NC][E];
    __shared__ float s_b[NC][E];
    __shared__ float s_old[NC][E];
    __shared__ float s_new[NC][E];

    const float Z = gacc[ACC_P + h*8 + c];
    float s = 0.0f;
    for (int j = 0; j < 64; ++j) s += gacc[ACC_SXW + (h*64 + j)*8 + c] * Wv[e*64 + j];
    s_a[c][e] = bv[e] + s / Z;
    __syncthreads();

    float s2 = bo[e];
    for (int j = 0; j < 64; ++j) s2 += s_a[c][j] * Wo[e*64 + j];
    s_b[c][e] = s2;
    const float cnt = gacc[ACC_CNT + c];
    const float oldv = gacc[ACC_AXS + e*8 + c] / fmaxf(cnt, 1.0f);
    s_old[c][e] = oldv;
    __syncthreads();

    float s3 = br[e];
    for (int j = 0; j < 64; ++j) s3 += sem[c*64 + j] * Wr[e*128 + j];
    for (int j = 0; j < 64; ++j) s3 += s_b[c][j]    * Wr[e*128 + 64 + j];
    s_new[c][e] = s3;
    __syncthreads();

    float s4 = bg[e];
    for (int j = 0; j < 64; ++j) s4 += s_old[c][j] * Wg[e*128 + j];
    for (int j = 0; j < 64; ++j) s4 += s_new[c][j] * Wg[e*128 + 64 + j];
    const float g = 1.0f / (1.0f + __expf(-s4));
    const float f = g * oldv + (1.0f - g) * s3;

    float sum = f;
    for (int m = 32; m >= 1; m >>= 1) sum += __shfl_xor(sum, m, 64);
    const float mu = sum * (1.0f/64.0f);
    const float d  = f - mu;
    float sq = d * d;
    for (int m = 32; m >= 1; m >>= 1) sq += __shfl_xor(sq, m, 64);
    const float var = sq * (1.0f/64.0f);
    fused[c*64 + e] = d * rsqrtf(var + 1e-5f) * gamma[e] + beta[e];
}

// ---------------- kernel D: out[n] = fused[cls[n]] * x[n] ----------------
__global__ __launch_bounds__(256) void kD(
    const float* __restrict__ xv, const float* __restrict__ xc,
    const int* __restrict__ clsv, const int* __restrict__ clsc,
    const float* __restrict__ ws, float* __restrict__ out)
{
    const int stride = gridDim.x * blockDim.x;
    const int TOT = 2 * N_NODES * 16;
    for (int i = blockIdx.x * blockDim.x + threadIdx.x; i < TOT; i += stride) {
        const int side  = i >= N_NODES * 16;
        const int local = side ? i - N_NODES * 16 : i;
        const int n = local >> 4;
        const int cc = side ? clsc[n] : clsv[n];
        const float* fu = ws + (side ? OFF_FUSED_C : OFF_FUSED_V);
        const float4 f  = reinterpret_cast<const float4*>(fu)[cc*16 + (local & 15)];
        const float* x  = side ? xc : xv;
        const float4 x4 = reinterpret_cast<const float4*>(x)[local];
        float4 o;
        o.x = f.x * x4.x; o.y = f.y * x4.y; o.z = f.z * x4.z; o.w = f.w * x4.w;
        reinterpret_cast<float4*>(out)[i] = o;
    }
}

extern "C" void kernel_launch(void* const* d_in, const int* in_sizes, int n_in,
                              void* d_out, int out_size, void* d_ws, size_t ws_size,
                              hipStream_t stream) {
    const float* v      = (const float*)d_in[0];
    const float* c      = (const float*)d_in[1];
    const float* v_sem  = (const float*)d_in[2];
    const float* c_sem  = (const float*)d_in[3];
    const int*   v_cls  = (const int*)d_in[4];
    const int*   c_cls  = (const int*)d_in[5];
    const float* Ws_v   = (const float*)d_in[6],  *bs_v   = (const float*)d_in[7];
    const float* Ws_c   = (const float*)d_in[8],  *bs_c   = (const float*)d_in[9];
    const float* Wqkv_v = (const float*)d_in[10], *bqkv_v = (const float*)d_in[11];
    const float* Wo_v   = (const float*)d_in[12], *bo_v   = (const float*)d_in[13];
    const float* Wqkv_c = (const float*)d_in[14], *bqkv_c = (const float*)d_in[15];
    const float* Wo_c   = (const float*)d_in[16], *bo_c   = (const float*)d_in[17];
    const float* Wr_v   = (const float*)d_in[18], *br_v   = (const float*)d_in[19];
    const float* Wr_c   = (const float*)d_in[20], *br_c   = (const float*)d_in[21];
    const float* Wg_v   = (const float*)d_in[22], *bg_v   = (const float*)d_in[23];
    const float* Wg_c   = (const float*)d_in[24], *bg_c   = (const float*)d_in[25];
    const float* gamma  = (const float*)d_in[26], *beta   = (const float*)d_in[27];
    float* ws  = (float*)d_ws;
    float* out = (float*)d_out;

    kQ<<<2, 512, 0, stream>>>(v_sem, c_sem, Wqkv_v, bqkv_v, Wqkv_c, bqkv_c,
                              Ws_v, bs_v, Ws_c, bs_c, ws);
    kA<<<2*BPS3, 256, 0, stream>>>(v, c, v_cls, c_cls, Ws_v, bs_v, Ws_c, bs_c, ws);
    kC<<<2, 512, 0, stream>>>(v_sem, c_sem, Wqkv_v, bqkv_v, Wqkv_c, bqkv_c,
                              Wo_v, bo_v, Wo_c, bo_c, Wr_v, br_v, Wr_c, br_c,
                              Wg_v, bg_v, Wg_c, bg_c, gamma, beta, ws);
    kD<<<4096, 256, 0, stream>>>(v, c, v_cls, c_cls, ws, out);
}